// Round 18
// baseline (108.159 us; speedup 1.0000x reference)
//
#include <hip/hip_runtime.h>
#include <hip/hip_bf16.h>

#define IN_F   64
#define OUT_F  64
#define N_RELS 32
#define N_BAS  30
#define KROW   2048               // k' = b*64 + i  (b slot 0..31, i feature 0..63)
#define B1CHUNK 2048

typedef __attribute__((ext_vector_type(8))) short short8v;
typedef __attribute__((ext_vector_type(4))) _Float16 half4v;
typedef __attribute__((ext_vector_type(4))) float f32x4;
typedef __attribute__((ext_vector_type(4))) unsigned u32x4;
typedef __attribute__((ext_vector_type(2))) unsigned u32x2;

// legacy spelling (gfx908-lineage): no underscore before dtype. Host-pass-safe.
#define MFMA16(a, b, c) __builtin_amdgcn_mfma_f32_16x16x16f16(a, b, c, 0, 0, 0)

__device__ __forceinline__ int dmin(int a, int b) { return a < b ? a : b; }
__device__ __forceinline__ unsigned short f2bf(float f) {
    __hip_bfloat16 h = __float2bfloat16(f);
    return *(unsigned short*)&h;
}

// ---------- K_prep: fused {bbt | xpack | b1a} via blockIdx range dispatch ----------
__global__ void __launch_bounds__(256)
k_prep(const float* __restrict__ basis, const float* __restrict__ sw,
       const float* __restrict__ bias, __hip_bfloat16* __restrict__ bbT,
       const float* __restrict__ x, unsigned* __restrict__ xh,
       const int* __restrict__ tgt, int* __restrict__ gsum,
       int N, int E, int nxp) {
    int bb = blockIdx.x;
    int tid = threadIdx.x;
    if (bb < 512) {                       // ---- bbt (fragment order, k' = b*64+i) ----
        int idx = bb * 256 + tid;
        int e = idx & 7, lane = (idx >> 3) & 63, s = (idx >> 9) & 15, kq = (idx >> 13) & 3, cb = idx >> 15;
        int l15 = lane & 15, lk = lane >> 4;
        int o = cb * 16 + l15;
        int k = kq * 512 + s * 32 + lk * 8 + e;
        int b = k >> 6, i = k & 63;
        float v;
        if (b < N_BAS)      v = basis[((size_t)b * IN_F + i) * OUT_F + o];
        else if (b == 30)   v = sw[(size_t)i * OUT_F + o];
        else                v = (i == 0) ? bias[o] : 0.f;
        bbT[idx] = __float2bfloat16(v);
    } else if (bb < 512 + nxp) {          // ---- xpack (rows 0..N; row N = zeros) ----
        int idx = (bb - 512) * 256 + tid;
        if (idx < (N + 1) * 32) {
            int g = idx & 31, n = idx >> 5;
            unsigned v = 0;
            if (n < N) {
                int f = (g & 15) + ((g >> 4) << 5);
                _Float16 lo = (_Float16)x[((size_t)n << 6) + f];
                _Float16 hi = (_Float16)x[((size_t)n << 6) + f + 16];
                v = (unsigned)*(unsigned short*)&lo | ((unsigned)*(unsigned short*)&hi << 16);
            }
            xh[idx] = v;
        }
    } else {                              // ---- b1a (LDS-staged coarse histogram) ----
        __shared__ int lh[256];
        int vb = bb - 512 - nxp;          // 0..255
        lh[tid] = 0;
        __syncthreads();
        for (int i = vb * 256 + tid; i < E; i += 256 * 256)
            atomicAdd(&lh[tgt[i] >> 8], 1);
        __syncthreads();
        if (lh[tid]) atomicAdd(&gsum[tid], lh[tid]);
    }
}

// ---------- K3: tiny scan of coarse buckets ----------
__global__ void k_scanB(const int* __restrict__ gsum, int* __restrict__ gexcl,
                        int* __restrict__ bcur, int* __restrict__ off, int NB, int N) {
    int l = threadIdx.x;
    int a0 = (4*l+0 < NB) ? gsum[4*l+0] : 0;
    int a1 = (4*l+1 < NB) ? gsum[4*l+1] : 0;
    int a2 = (4*l+2 < NB) ? gsum[4*l+2] : 0;
    int a3 = (4*l+3 < NB) ? gsum[4*l+3] : 0;
    int s = a0 + a1 + a2 + a3;
    int sc = s;
    for (int d = 1; d < 64; d <<= 1) {
        int o = __shfl_up(sc, d, 64);
        if (l >= d) sc += o;
    }
    int base = sc - s;
    if (4*l+0 < NB) { gexcl[4*l+0] = base;          bcur[4*l+0] = base; }
    if (4*l+1 < NB) { gexcl[4*l+1] = base+a0;       bcur[4*l+1] = base+a0; }
    if (4*l+2 < NB) { gexcl[4*l+2] = base+a0+a1;    bcur[4*l+2] = base+a0+a1; }
    if (4*l+3 < NB) { gexcl[4*l+3] = base+a0+a1+a2; bcur[4*l+3] = base+a0+a1+a2; }
    if (l == 63) { gexcl[NB] = sc; off[N] = sc; }
}

// ---------- K4: coarse bucket scatter (2048-edge chunks x 512 thr -> 391 blocks) ----------
__global__ void __launch_bounds__(512)
k_b1(const int* __restrict__ src, const int* __restrict__ tgt, const int* __restrict__ et,
     int* __restrict__ bcur, unsigned* __restrict__ ssr, int E) {
    __shared__ unsigned ls_p[B1CHUNK];
    __shared__ unsigned char ls_b[B1CHUNK];
    __shared__ int lh[256], lbase[256], gbase[256], lcur[256];
    int tid = threadIdx.x;
    int e0 = blockIdx.x * B1CHUNK;
    int n = E - e0; if (n > B1CHUNK) n = B1CHUNK;
    if (tid < 256) { lh[tid] = 0; lcur[tid] = 0; }
    __syncthreads();
    unsigned pr[4]; int br[4];
#pragma unroll
    for (int k = 0; k < 4; ++k) {
        int i = k * 512 + tid;
        br[k] = -1;
        if (i < n) {
            int t = tgt[e0 + i];
            br[k] = t >> 8;
            pr[k] = ((unsigned)(t & 255) << 21) | ((unsigned)src[e0 + i] << 5) | (unsigned)et[e0 + i];
            atomicAdd(&lh[br[k]], 1);
        }
    }
    __syncthreads();
    if (tid < 64) {
        int a0 = lh[4*tid], a1 = lh[4*tid+1], a2 = lh[4*tid+2], a3 = lh[4*tid+3];
        int s = a0 + a1 + a2 + a3, sc = s;
        for (int d = 1; d < 64; d <<= 1) {
            int o = __shfl_up(sc, d, 64);
            if (tid >= d) sc += o;
        }
        int base = sc - s;
        lbase[4*tid] = base; lbase[4*tid+1] = base+a0;
        lbase[4*tid+2] = base+a0+a1; lbase[4*tid+3] = base+a0+a1+a2;
    }
    __syncthreads();
    if (tid < 256 && lh[tid]) gbase[tid] = atomicAdd(&bcur[tid], lh[tid]);
    __syncthreads();
#pragma unroll
    for (int k = 0; k < 4; ++k) {
        if (br[k] >= 0) {
            int pos = atomicAdd(&lcur[br[k]], 1);
            int s = lbase[br[k]] + pos;
            ls_p[s] = pr[k];
            ls_b[s] = (unsigned char)br[k];
        }
    }
    __syncthreads();
#pragma unroll
    for (int k = 0; k < 4; ++k) {
        int i = k * 512 + tid;
        if (i < n) {
            int b = ls_b[i];
            ssr[gbase[b] + (i - lbase[b])] = ls_p[i];
        }
    }
}

// ---------- K5: per-bucket fine sort (1024 threads) ----------
__global__ void __launch_bounds__(1024)
k_b2(const unsigned* __restrict__ ssr, const int* __restrict__ gexcl,
     int* __restrict__ off, unsigned* __restrict__ ssr2, int N) {
    __shared__ int lh[256], lofs[256], lcur[256];
    int g = blockIdx.x, tid = threadIdx.x;
    int o0 = gexcl[g], o1 = gexcl[g + 1];
    if (tid < 256) lh[tid] = 0;
    __syncthreads();
    for (int i = o0 + tid; i < o1; i += 1024)
        atomicAdd(&lh[ssr[i] >> 21], 1);
    __syncthreads();
    if (tid < 64) {
        int a0 = lh[4*tid], a1 = lh[4*tid+1], a2 = lh[4*tid+2], a3 = lh[4*tid+3];
        int s = a0 + a1 + a2 + a3, sc = s;
        for (int d = 1; d < 64; d <<= 1) {
            int o = __shfl_up(sc, d, 64);
            if (tid >= d) sc += o;
        }
        int base = sc - s;
        lofs[4*tid] = base; lofs[4*tid+1] = base+a0;
        lofs[4*tid+2] = base+a0+a1; lofs[4*tid+3] = base+a0+a1+a2;
    }
    __syncthreads();
    if (tid < 256) {
        int t = (g << 8) + tid;
        if (t < N) off[t] = o0 + lofs[tid];
        lcur[tid] = o0 + lofs[tid];
    }
    __syncthreads();
    for (int i = o0 + tid; i < o1; i += 1024) {
        unsigned p = ssr[i];
        int pos = atomicAdd(&lcur[p >> 21], 1);
        ssr2[pos] = p;
    }
}

// ---------- edge round: K=16 MFMA, select-free staged loop + est-word pipeline ----------
__device__ __forceinline__ void edge_round(
    unsigned char* zb, const unsigned* cofs2, const unsigned* est,
    const unsigned* __restrict__ ssr2, const char* __restrict__ xhB,
    int tIdx, int s0r, int s1r, float xselfv,
    int mh, int l15, int lk, unsigned xadd2, unsigned cbase, u32x4 w0)
{
    int deg = s1r - s0r;
    int sbase = lk << 2;                   // edge-slot base of this quadrant (4 slots)
    f32x4 acc00 = {0.f,0.f,0.f,0.f};
    f32x4 acc01 = acc00, acc10 = acc00, acc11 = acc00;
    if (deg > 0) {
        if (deg <= 128) {                  // staged: pre-padded to x16 (select-free), est pipelined
            int nt = (deg + 15) >> 4;
#pragma unroll 1
            for (int kt = 0; kt < nt; ++kt) {
                u32x4 wn = w0;
                if (kt + 1 < nt)           // prefetch next tile's est word
                    wn = *(const u32x4*)((const unsigned char*)(est + tIdx * 128 + (kt + 1) * 16 + sbase));
                union { unsigned short u[4]; half4v h; } bf0, bf1, a0, a1;
#pragma unroll
                for (int j = 0; j < 4; ++j) {
                    unsigned wj = w0[j];
                    unsigned bw = cofs2[cbase + ((wj & 31u) << 4) + l15];
                    unsigned xw = *(const unsigned*)(xhB + (((size_t)((wj >> 5) & 0xFFFFu)) << 7) + xadd2);
                    bf0.u[j] = (unsigned short)(bw & 0xFFFFu);
                    bf1.u[j] = (unsigned short)(bw >> 16);
                    a0.u[j]  = (unsigned short)(xw & 0xFFFFu);
                    a1.u[j]  = (unsigned short)(xw >> 16);
                }
                acc00 = MFMA16(a0.h, bf0.h, acc00);
                acc01 = MFMA16(a0.h, bf1.h, acc01);
                acc10 = MFMA16(a1.h, bf0.h, acc10);
                acc11 = MFMA16(a1.h, bf1.h, acc11);
                w0 = wn;
            }
        } else {                           // rare fallback (deg>128): global + bpermute + selects
            int last = s1r - 1;
#pragma unroll 1
            for (int kt = 0; kt * 16 < deg; ++kt) {
                int rem = deg - kt * 16;
                unsigned ew = ssr2[dmin(s0r + kt * 16 + l15, last)];
                union { unsigned short u[4]; half4v h; } bf0, bf1, a0, a1;
#pragma unroll
                for (int j = 0; j < 4; ++j) {
                    unsigned wj = (unsigned)__builtin_amdgcn_ds_bpermute((lk << 4) + j * 4, (int)ew);
                    bool okj = (sbase + j) < rem;
                    unsigned rrow = okj ? (wj & 31u) : 32u;
                    unsigned wjs  = okj ? wj : 0u;
                    unsigned bw = cofs2[cbase + (rrow << 4) + l15];
                    unsigned xw = *(const unsigned*)(xhB + (((size_t)((wjs >> 5) & 0xFFFFu)) << 7) + xadd2);
                    bf0.u[j] = (unsigned short)(bw & 0xFFFFu);
                    bf1.u[j] = (unsigned short)(bw >> 16);
                    a0.u[j]  = (unsigned short)(xw & 0xFFFFu);
                    a1.u[j]  = (unsigned short)(xw >> 16);
                }
                acc00 = MFMA16(a0.h, bf0.h, acc00);
                acc01 = MFMA16(a0.h, bf1.h, acc01);
                acc10 = MFMA16(a1.h, bf0.h, acc10);
                acc11 = MFMA16(a1.h, bf1.h, acc11);
            }
        }
    }
    // epilogue (b-major zb): byte = b*128 + i*2, XORs: row swz + ((byte>>7)&7)<<4
    float inv = 1.f / fmaxf((float)deg, 1.f);
    unsigned rb = (unsigned)tIdx << 12;
    unsigned swz = (unsigned)((tIdx & 7) << 4);
    unsigned ib = (unsigned)((mh << 5) + (lk << 2));   // i base (q packs 4 consecutive)
    {
        unsigned short h0, h1, h2, h3;
        u32x2 pv;
        h0 = f2bf(acc00[0]*inv); h1 = f2bf(acc00[1]*inv); h2 = f2bf(acc00[2]*inv); h3 = f2bf(acc00[3]*inv);
        pv[0] = h0 | ((unsigned)h1 << 16); pv[1] = h2 | ((unsigned)h3 << 16);
        unsigned byt = ((unsigned)l15 << 7) + (ib << 1);
        byt ^= swz ^ (((byt >> 7) & 7) << 4);
        *(u32x2*)(zb + rb + byt) = pv;
        h0 = f2bf(acc01[0]*inv); h1 = f2bf(acc01[1]*inv); h2 = f2bf(acc01[2]*inv); h3 = f2bf(acc01[3]*inv);
        pv[0] = h0 | ((unsigned)h1 << 16); pv[1] = h2 | ((unsigned)h3 << 16);
        byt = ((unsigned)(16 + l15) << 7) + (ib << 1);
        byt ^= swz ^ (((byt >> 7) & 7) << 4);
        *(u32x2*)(zb + rb + byt) = pv;
        h0 = f2bf(acc10[0]*inv); h1 = f2bf(acc10[1]*inv); h2 = f2bf(acc10[2]*inv); h3 = f2bf(acc10[3]*inv);
        pv[0] = h0 | ((unsigned)h1 << 16); pv[1] = h2 | ((unsigned)h3 << 16);
        byt = ((unsigned)l15 << 7) + ((ib + 16) << 1);
        byt ^= swz ^ (((byt >> 7) & 7) << 4);
        *(u32x2*)(zb + rb + byt) = pv;
        h0 = f2bf(acc11[0]*inv); h1 = f2bf(acc11[1]*inv); h2 = f2bf(acc11[2]*inv); h3 = f2bf(acc11[3]*inv);
        pv[0] = h0 | ((unsigned)h1 << 16); pv[1] = h2 | ((unsigned)h3 << 16);
        byt = ((unsigned)(16 + l15) << 7) + ((ib + 16) << 1);
        byt ^= swz ^ (((byt >> 7) & 7) << 4);
        *(u32x2*)(zb + rb + byt) = pv;
    }
    int lane = (lk << 4) + l15;
    if (lane < 32) {                                 // b=30 row: xself at i = mh*32+lane
        unsigned byt = (30u << 7) + ((unsigned)((mh << 5) + lane) << 1);
        byt ^= swz ^ (((byt >> 7) & 7) << 4);
        *(unsigned short*)(zb + rb + byt) = f2bf(xselfv);
        if (mh == 0 && lane == 0) {                  // b=31 @ i=0: 1.0 (bias hot-one)
            unsigned byb = (31u << 7);
            byb ^= swz ^ (((byb >> 7) & 7) << 4);
            *(unsigned short*)(zb + rb + byb) = (unsigned short)0x3F80;
        }
    }
}

// ---------- K6: fused v18 (unchanged from R17) ----------
__global__ void __launch_bounds__(1024, 8)
k_fused(const float* __restrict__ x, const unsigned* __restrict__ xh,
        const unsigned* __restrict__ ssr2, const int* __restrict__ off,
        const float* __restrict__ coeff, const __hip_bfloat16* __restrict__ bbT,
        float* __restrict__ out, int N) {
    __shared__ __align__(16) unsigned char zb[16 * 4096];   // 16 targets x 2048 bf16 (b-major), swizzled
    __shared__ __align__(16) float pf[16 * 256];            // phase-2 partials; head aliases cofs2+est
    unsigned* cofs2 = (unsigned*)pf;                        // 2 copies [33][16] u32, stride 560 words
    unsigned* est   = ((unsigned*)pf) + 1120;               // 16 slots x 128 words (16B aligned)
    int tid = threadIdx.x;
    int w = tid >> 6, lane = tid & 63;
    int mh = w & 1;
    int t0 = blockIdx.x * 16;

    // hoisted per-round loads (scalars only)
    int tA = t0 + (w >> 1), tB = tA + 8;
    int okA = (tA < N), okB = (tB < N);
    int offA0 = okA ? off[tA] : 0;
    int offA1 = okA ? off[tA + 1] : 0;
    int offB0 = okB ? off[tB] : 0;
    int offB1 = okB ? off[tB + 1] : 0;
    float xsA = okA ? x[((size_t)tA << 6) + (mh << 5) + (lane & 31)] : 0.f;
    float xsB = okB ? x[((size_t)tB << 6) + (mh << 5) + (lane & 31)] : 0.f;

    int s0A = __builtin_amdgcn_readfirstlane(offA0);
    int s1A = __builtin_amdgcn_readfirstlane(offA1);
    int s0B = __builtin_amdgcn_readfirstlane(offB0);
    int s1B = __builtin_amdgcn_readfirstlane(offB1);

    // stage coeff pairs -> LDS (2 bank-offset copies)
    for (int idx = tid; idx < 33 * 16; idx += 1024) {
        int r = idx >> 4, c = idx & 15;
        float lo = (r < 32) ? coeff[r * N_BAS + c] : 0.f;
        float hi = (r < 32 && (c + 16) < N_BAS) ? coeff[r * N_BAS + c + 16] : 0.f;
        _Float16 hl = (_Float16)lo, hh = (_Float16)hi;
        unsigned v = (unsigned)*(unsigned short*)&hl | ((unsigned)*(unsigned short*)&hh << 16);
        cofs2[idx] = v;
        cofs2[idx + 560] = v;
    }
    // stage edge words; pad to x16 with PADW = (N<<5): node N = zero x-row -> exact 0 contribution
    {
        unsigned PADW = (unsigned)N << 5;
        int sgt = mh ? s0B : s0A;
        int sg1 = mh ? s1B : s1A;
        int slot = (w >> 1) + (mh << 3);
        int degS = sg1 - sgt;
        if (degS > 0 && degS <= 128) {
            int pe = (degS + 15) & ~15;
            if (lane < degS)           est[slot * 128 + lane] = ssr2[sgt + lane];
            else if (lane < pe)        est[slot * 128 + lane] = PADW;
            if (lane + 64 < degS)      est[slot * 128 + lane + 64] = ssr2[sgt + lane + 64];
            else if (lane + 64 < pe)   est[slot * 128 + lane + 64] = PADW;
        }
    }
    __syncthreads();

    int l15 = lane & 15, lk = lane >> 4;
    int sbase = lk << 2;
    unsigned xadd2 = (unsigned)(((mh << 4) + l15) << 2);   // xh entry g = mh*16+l15, bytes
    const char* xhB = (const char*)xh;
    unsigned cbase = (unsigned)((lk & 1) * 560);           // cofs copy for this quadrant

    // cross-round est prefetch: both rounds' tile-0 words issue here
    int degA = s1A - s0A, degB = s1B - s0B;
    u32x4 wA0 = {0u, 0u, 0u, 0u}, wB0 = {0u, 0u, 0u, 0u};
    if (degA > 0 && degA <= 128)
        wA0 = *(const u32x4*)((const unsigned char*)(est + (w >> 1) * 128 + sbase));
    if (degB > 0 && degB <= 128)
        wB0 = *(const u32x4*)((const unsigned char*)(est + ((w >> 1) + 8) * 128 + sbase));

    edge_round(zb, cofs2, est, ssr2, xhB, (w >> 1),     s0A, s1A, xsA,
               mh, l15, lk, xadd2, cbase, wA0);
    edge_round(zb, cofs2, est, ssr2, xhB, (w >> 1) + 8, s0B, s1B, xsB,
               mh, l15, lk, xadd2, cbase, wB0);
    __syncthreads();

    // ---- phase 2: wave w -> colblk=w&3, K-quarter kq=w>>2 (512 each, 16 steps);
    //      A from b-major zb (abyte formula + dual XOR); B contiguous 1KB/step from bbT
    {
        int colblk = w & 3, kq = w >> 2;
        const char* bp2 = (const char*)bbT + (((unsigned)(colblk * 4 + kq)) << 14) + ((unsigned)lane << 4);
        unsigned arow = (unsigned)l15 << 12;
        unsigned aswz = (unsigned)((l15 & 7) << 4);
        f32x4 acc2 = {0.f,0.f,0.f,0.f};
#pragma unroll 4
        for (int s = 0; s < 16; ++s) {
            unsigned abyte = (unsigned)((kq << 10) + (s << 6) + (lk << 4));
            abyte ^= aswz ^ (((abyte >> 7) & 7) << 4);
            short8v a = *(const short8v*)(zb + arow + abyte);
            short8v b = *(const short8v*)(bp2 + (s << 10));
            acc2 = __builtin_amdgcn_mfma_f32_16x16x32_bf16(a, b, acc2, 0, 0, 0);
        }
#pragma unroll
        for (int q = 0; q < 4; ++q)                      // D: col=l15, row=lk*4+q (row = target)
            pf[(w << 8) + ((lk << 2) + q) * 16 + l15] = acc2[q];
    }
    __syncthreads();

    // ---- reduce 4 K-quarters + write (1024 threads = 16 targets x 64 cols)
    {
        int row = w, col = lane;
        int cb = col >> 4, cl = col & 15;
        int tt = t0 + row;
        if (tt < N) {
            float v = pf[(((0 << 2) + cb) << 8) + (row << 4) + cl]
                    + pf[(((1 << 2) + cb) << 8) + (row << 4) + cl]
                    + pf[(((2 << 2) + cb) << 8) + (row << 4) + cl]
                    + pf[(((3 << 2) + cb) << 8) + (row << 4) + cl];
            out[((size_t)tt << 6) + col] = v;
        }
    }
}

extern "C" void kernel_launch(void* const* d_in, const int* in_sizes, int n_in,
                              void* d_out, int out_size, void* d_ws, size_t ws_size,
                              hipStream_t stream) {
    const float* x     = (const float*)d_in[0];
    const int*   eidx  = (const int*)d_in[1];   // (2, E)
    const int*   etype = (const int*)d_in[2];
    const float* basis = (const float*)d_in[4];
    const float* coeff = (const float*)d_in[5];
    const float* sw    = (const float*)d_in[6];
    const float* bias  = (const float*)d_in[7];

    const int E = in_sizes[1] / 2;
    const int N = out_size / OUT_F;
    const int NB = (N + 255) >> 8;
    const int* srcv = eidx;
    const int* tgtv = eidx + E;
    float* out = (float*)d_out;

    size_t p = 0;
    auto alloc = [&](size_t bytes) { size_t cur = p; p += (bytes + 255) & ~(size_t)255; return cur; };
    char* base = (char*)d_ws;
    __hip_bfloat16* bbT   = (__hip_bfloat16*)(base + alloc((size_t)OUT_F * KROW * 2));
    int*            gsum  = (int*)(base + alloc(256 * 4));
    int*            gexcl = (int*)(base + alloc((size_t)(NB + 1) * 4));
    int*            bcur  = (int*)(base + alloc((size_t)NB * 4));
    int*            off   = (int*)(base + alloc((size_t)(N + 1) * 4));
    unsigned*       ssr   = (unsigned*)(base + alloc((size_t)E * 4));
    unsigned*       ssr2  = (unsigned*)(base + alloc((size_t)E * 4));
    unsigned*       xh    = (unsigned*)(base + alloc((size_t)(N + 1) * 32 * 4));
    (void)ws_size;

    hipMemsetAsync(gsum, 0, 256 * 4, stream);

    const int nxp = ((N + 1) * 32 + 255) >> 8;
    k_prep<<<512 + nxp + 256, 256, 0, stream>>>(basis, sw, bias, bbT, x, xh, tgtv, gsum, N, E, nxp);
    k_scanB<<<1, 64, 0, stream>>>(gsum, gexcl, bcur, off, NB, N);
    k_b1<<<(E + B1CHUNK - 1) / B1CHUNK, 512, 0, stream>>>(srcv, tgtv, etype, bcur, ssr, E);
    k_b2<<<NB, 1024, 0, stream>>>(ssr, gexcl, off, ssr2, N);
    k_fused<<<(N + 15) / 16, 1024, 0, stream>>>(x, xh, ssr2, off, coeff, bbT, out, N);
}

// Round 19
// 104.772 us; speedup vs baseline: 1.0323x; 1.0323x over previous
//
#include <hip/hip_runtime.h>
#include <hip/hip_bf16.h>

#define IN_F   64
#define OUT_F  64
#define N_RELS 32
#define N_BAS  30
#define KROW   2048               // k' = b*64 + i  (b slot 0..31, i feature 0..63)
#define B1CHUNK 4096

typedef __attribute__((ext_vector_type(8))) short short8v;
typedef __attribute__((ext_vector_type(4))) _Float16 half4v;
typedef __attribute__((ext_vector_type(4))) float f32x4;
typedef __attribute__((ext_vector_type(4))) unsigned u32x4;
typedef __attribute__((ext_vector_type(2))) unsigned u32x2;

// legacy spelling (gfx908-lineage): no underscore before dtype. Host-pass-safe.
#define MFMA16(a, b, c) __builtin_amdgcn_mfma_f32_16x16x16f16(a, b, c, 0, 0, 0)

__device__ __forceinline__ int dmin(int a, int b) { return a < b ? a : b; }
__device__ __forceinline__ unsigned short f2bf(float f) {
    __hip_bfloat16 h = __float2bfloat16(f);
    return *(unsigned short*)&h;
}

// ---------- K_prep: fused {bbt | xpack | b1a} via blockIdx range dispatch ----------
__global__ void __launch_bounds__(256)
k_prep(const float* __restrict__ basis, const float* __restrict__ sw,
       const float* __restrict__ bias, __hip_bfloat16* __restrict__ bbT,
       const float* __restrict__ x, unsigned* __restrict__ xh,
       const int* __restrict__ tgt, int* __restrict__ gsum,
       int N, int E, int nxp) {
    int bb = blockIdx.x;
    int tid = threadIdx.x;
    if (bb < 512) {                       // ---- bbt (fragment order, k' = b*64+i) ----
        int idx = bb * 256 + tid;
        int e = idx & 7, lane = (idx >> 3) & 63, s = (idx >> 9) & 15, kq = (idx >> 13) & 3, cb = idx >> 15;
        int l15 = lane & 15, lk = lane >> 4;
        int o = cb * 16 + l15;
        int k = kq * 512 + s * 32 + lk * 8 + e;
        int b = k >> 6, i = k & 63;
        float v;
        if (b < N_BAS)      v = basis[((size_t)b * IN_F + i) * OUT_F + o];
        else if (b == 30)   v = sw[(size_t)i * OUT_F + o];
        else                v = (i == 0) ? bias[o] : 0.f;
        bbT[idx] = __float2bfloat16(v);
    } else if (bb < 512 + nxp) {          // ---- xpack (rows 0..N; row N = zeros) ----
        int idx = (bb - 512) * 256 + tid;
        if (idx < (N + 1) * 32) {
            int g = idx & 31, n = idx >> 5;
            unsigned v = 0;
            if (n < N) {
                int f = (g & 15) + ((g >> 4) << 5);
                _Float16 lo = (_Float16)x[((size_t)n << 6) + f];
                _Float16 hi = (_Float16)x[((size_t)n << 6) + f + 16];
                v = (unsigned)*(unsigned short*)&lo | ((unsigned)*(unsigned short*)&hi << 16);
            }
            xh[idx] = v;
        }
    } else {                              // ---- b1a (LDS-staged coarse histogram) ----
        __shared__ int lh[256];
        int vb = bb - 512 - nxp;          // 0..255
        lh[tid] = 0;
        __syncthreads();
        for (int i = vb * 256 + tid; i < E; i += 256 * 256)
            atomicAdd(&lh[tgt[i] >> 8], 1);
        __syncthreads();
        if (lh[tid]) atomicAdd(&gsum[tid], lh[tid]);
    }
}

// ---------- K3: tiny scan of coarse buckets ----------
__global__ void k_scanB(const int* __restrict__ gsum, int* __restrict__ gexcl,
                        int* __restrict__ bcur, int* __restrict__ off, int NB, int N) {
    int l = threadIdx.x;
    int a0 = (4*l+0 < NB) ? gsum[4*l+0] : 0;
    int a1 = (4*l+1 < NB) ? gsum[4*l+1] : 0;
    int a2 = (4*l+2 < NB) ? gsum[4*l+2] : 0;
    int a3 = (4*l+3 < NB) ? gsum[4*l+3] : 0;
    int s = a0 + a1 + a2 + a3;
    int sc = s;
    for (int d = 1; d < 64; d <<= 1) {
        int o = __shfl_up(sc, d, 64);
        if (l >= d) sc += o;
    }
    int base = sc - s;
    if (4*l+0 < NB) { gexcl[4*l+0] = base;          bcur[4*l+0] = base; }
    if (4*l+1 < NB) { gexcl[4*l+1] = base+a0;       bcur[4*l+1] = base+a0; }
    if (4*l+2 < NB) { gexcl[4*l+2] = base+a0+a1;    bcur[4*l+2] = base+a0+a1; }
    if (4*l+3 < NB) { gexcl[4*l+3] = base+a0+a1+a2; bcur[4*l+3] = base+a0+a1+a2; }
    if (l == 63) { gexcl[NB] = sc; off[N] = sc; }
}

// ---------- K4: coarse bucket scatter (4096-edge chunks, 1024 threads, LDS-staged) ----------
__global__ void __launch_bounds__(1024)
k_b1(const int* __restrict__ src, const int* __restrict__ tgt, const int* __restrict__ et,
     int* __restrict__ bcur, unsigned* __restrict__ ssr, int E) {
    __shared__ unsigned ls_p[B1CHUNK];
    __shared__ unsigned char ls_b[B1CHUNK];
    __shared__ int lh[256], lbase[256], gbase[256], lcur[256];
    int tid = threadIdx.x;
    int e0 = blockIdx.x * B1CHUNK;
    int n = E - e0; if (n > B1CHUNK) n = B1CHUNK;
    if (tid < 256) { lh[tid] = 0; lcur[tid] = 0; }
    __syncthreads();
    unsigned pr[4]; int br[4];
#pragma unroll
    for (int k = 0; k < 4; ++k) {
        int i = k * 1024 + tid;
        br[k] = -1;
        if (i < n) {
            int t = tgt[e0 + i];
            br[k] = t >> 8;
            pr[k] = ((unsigned)(t & 255) << 21) | ((unsigned)src[e0 + i] << 5) | (unsigned)et[e0 + i];
            atomicAdd(&lh[br[k]], 1);
        }
    }
    __syncthreads();
    if (tid < 64) {
        int a0 = lh[4*tid], a1 = lh[4*tid+1], a2 = lh[4*tid+2], a3 = lh[4*tid+3];
        int s = a0 + a1 + a2 + a3, sc = s;
        for (int d = 1; d < 64; d <<= 1) {
            int o = __shfl_up(sc, d, 64);
            if (tid >= d) sc += o;
        }
        int base = sc - s;
        lbase[4*tid] = base; lbase[4*tid+1] = base+a0;
        lbase[4*tid+2] = base+a0+a1; lbase[4*tid+3] = base+a0+a1+a2;
    }
    __syncthreads();
    if (tid < 256 && lh[tid]) gbase[tid] = atomicAdd(&bcur[tid], lh[tid]);
    __syncthreads();
#pragma unroll
    for (int k = 0; k < 4; ++k) {
        if (br[k] >= 0) {
            int pos = atomicAdd(&lcur[br[k]], 1);
            int s = lbase[br[k]] + pos;
            ls_p[s] = pr[k];
            ls_b[s] = (unsigned char)br[k];
        }
    }
    __syncthreads();
#pragma unroll
    for (int k = 0; k < 4; ++k) {
        int i = k * 1024 + tid;
        if (i < n) {
            int b = ls_b[i];
            ssr[gbase[b] + (i - lbase[b])] = ls_p[i];
        }
    }
}

// ---------- K5: per-bucket fine sort (1024 threads) ----------
__global__ void __launch_bounds__(1024)
k_b2(const unsigned* __restrict__ ssr, const int* __restrict__ gexcl,
     int* __restrict__ off, unsigned* __restrict__ ssr2, int N) {
    __shared__ int lh[256], lofs[256], lcur[256];
    int g = blockIdx.x, tid = threadIdx.x;
    int o0 = gexcl[g], o1 = gexcl[g + 1];
    if (tid < 256) lh[tid] = 0;
    __syncthreads();
    for (int i = o0 + tid; i < o1; i += 1024)
        atomicAdd(&lh[ssr[i] >> 21], 1);
    __syncthreads();
    if (tid < 64) {
        int a0 = lh[4*tid], a1 = lh[4*tid+1], a2 = lh[4*tid+2], a3 = lh[4*tid+3];
        int s = a0 + a1 + a2 + a3, sc = s;
        for (int d = 1; d < 64; d <<= 1) {
            int o = __shfl_up(sc, d, 64);
            if (tid >= d) sc += o;
        }
        int base = sc - s;
        lofs[4*tid] = base; lofs[4*tid+1] = base+a0;
        lofs[4*tid+2] = base+a0+a1; lofs[4*tid+3] = base+a0+a1+a2;
    }
    __syncthreads();
    if (tid < 256) {
        int t = (g << 8) + tid;
        if (t < N) off[t] = o0 + lofs[tid];
        lcur[tid] = o0 + lofs[tid];
    }
    __syncthreads();
    for (int i = o0 + tid; i < o1; i += 1024) {
        unsigned p = ssr[i];
        int pos = atomicAdd(&lcur[p >> 21], 1);
        ssr2[pos] = p;
    }
}

// ---------- edge round: K=16 MFMA, select-free staged loop + est-word pipeline ----------
__device__ __forceinline__ void edge_round(
    unsigned char* zb, const unsigned* cofs2, const unsigned* est,
    const unsigned* __restrict__ ssr2, const char* __restrict__ xhB,
    int tIdx, int s0r, int s1r, float xselfv,
    int mh, int l15, int lk, unsigned xadd2, unsigned cbase, u32x4 w0)
{
    int deg = s1r - s0r;
    int sbase = lk << 2;                   // edge-slot base of this quadrant (4 slots)
    f32x4 acc00 = {0.f,0.f,0.f,0.f};
    f32x4 acc01 = acc00, acc10 = acc00, acc11 = acc00;
    if (deg > 0) {
        if (deg <= 128) {                  // staged: pre-padded to x16 (select-free), est pipelined
            int nt = (deg + 15) >> 4;
#pragma unroll 1
            for (int kt = 0; kt < nt; ++kt) {
                u32x4 wn = w0;
                if (kt + 1 < nt)           // prefetch next tile's est word
                    wn = *(const u32x4*)((const unsigned char*)(est + tIdx * 128 + (kt + 1) * 16 + sbase));
                union { unsigned short u[4]; half4v h; } bf0, bf1, a0, a1;
#pragma unroll
                for (int j = 0; j < 4; ++j) {
                    unsigned wj = w0[j];
                    unsigned bw = cofs2[cbase + ((wj & 31u) << 4) + l15];
                    unsigned xw = *(const unsigned*)(xhB + (((size_t)((wj >> 5) & 0xFFFFu)) << 7) + xadd2);
                    bf0.u[j] = (unsigned short)(bw & 0xFFFFu);
                    bf1.u[j] = (unsigned short)(bw >> 16);
                    a0.u[j]  = (unsigned short)(xw & 0xFFFFu);
                    a1.u[j]  = (unsigned short)(xw >> 16);
                }
                acc00 = MFMA16(a0.h, bf0.h, acc00);
                acc01 = MFMA16(a0.h, bf1.h, acc01);
                acc10 = MFMA16(a1.h, bf0.h, acc10);
                acc11 = MFMA16(a1.h, bf1.h, acc11);
                w0 = wn;
            }
        } else {                           // rare fallback (deg>128): global + bpermute + selects
            int last = s1r - 1;
#pragma unroll 1
            for (int kt = 0; kt * 16 < deg; ++kt) {
                int rem = deg - kt * 16;
                unsigned ew = ssr2[dmin(s0r + kt * 16 + l15, last)];
                union { unsigned short u[4]; half4v h; } bf0, bf1, a0, a1;
#pragma unroll
                for (int j = 0; j < 4; ++j) {
                    unsigned wj = (unsigned)__builtin_amdgcn_ds_bpermute((lk << 4) + j * 4, (int)ew);
                    bool okj = (sbase + j) < rem;
                    unsigned rrow = okj ? (wj & 31u) : 32u;
                    unsigned wjs  = okj ? wj : 0u;
                    unsigned bw = cofs2[cbase + (rrow << 4) + l15];
                    unsigned xw = *(const unsigned*)(xhB + (((size_t)((wjs >> 5) & 0xFFFFu)) << 7) + xadd2);
                    bf0.u[j] = (unsigned short)(bw & 0xFFFFu);
                    bf1.u[j] = (unsigned short)(bw >> 16);
                    a0.u[j]  = (unsigned short)(xw & 0xFFFFu);
                    a1.u[j]  = (unsigned short)(xw >> 16);
                }
                acc00 = MFMA16(a0.h, bf0.h, acc00);
                acc01 = MFMA16(a0.h, bf1.h, acc01);
                acc10 = MFMA16(a1.h, bf0.h, acc10);
                acc11 = MFMA16(a1.h, bf1.h, acc11);
            }
        }
    }
    // epilogue (b-major zb): byte = b*128 + i*2, XORs: row swz + ((byte>>7)&7)<<4
    float inv = 1.f / fmaxf((float)deg, 1.f);
    unsigned rb = (unsigned)tIdx << 12;
    unsigned swz = (unsigned)((tIdx & 7) << 4);
    unsigned ib = (unsigned)((mh << 5) + (lk << 2));   // i base (q packs 4 consecutive)
    {
        unsigned short h0, h1, h2, h3;
        u32x2 pv;
        h0 = f2bf(acc00[0]*inv); h1 = f2bf(acc00[1]*inv); h2 = f2bf(acc00[2]*inv); h3 = f2bf(acc00[3]*inv);
        pv[0] = h0 | ((unsigned)h1 << 16); pv[1] = h2 | ((unsigned)h3 << 16);
        unsigned byt = ((unsigned)l15 << 7) + (ib << 1);
        byt ^= swz ^ (((byt >> 7) & 7) << 4);
        *(u32x2*)(zb + rb + byt) = pv;
        h0 = f2bf(acc01[0]*inv); h1 = f2bf(acc01[1]*inv); h2 = f2bf(acc01[2]*inv); h3 = f2bf(acc01[3]*inv);
        pv[0] = h0 | ((unsigned)h1 << 16); pv[1] = h2 | ((unsigned)h3 << 16);
        byt = ((unsigned)(16 + l15) << 7) + (ib << 1);
        byt ^= swz ^ (((byt >> 7) & 7) << 4);
        *(u32x2*)(zb + rb + byt) = pv;
        h0 = f2bf(acc10[0]*inv); h1 = f2bf(acc10[1]*inv); h2 = f2bf(acc10[2]*inv); h3 = f2bf(acc10[3]*inv);
        pv[0] = h0 | ((unsigned)h1 << 16); pv[1] = h2 | ((unsigned)h3 << 16);
        byt = ((unsigned)l15 << 7) + ((ib + 16) << 1);
        byt ^= swz ^ (((byt >> 7) & 7) << 4);
        *(u32x2*)(zb + rb + byt) = pv;
        h0 = f2bf(acc11[0]*inv); h1 = f2bf(acc11[1]*inv); h2 = f2bf(acc11[2]*inv); h3 = f2bf(acc11[3]*inv);
        pv[0] = h0 | ((unsigned)h1 << 16); pv[1] = h2 | ((unsigned)h3 << 16);
        byt = ((unsigned)(16 + l15) << 7) + ((ib + 16) << 1);
        byt ^= swz ^ (((byt >> 7) & 7) << 4);
        *(u32x2*)(zb + rb + byt) = pv;
    }
    int lane = (lk << 4) + l15;
    if (lane < 32) {                                 // b=30 row: xself at i = mh*32+lane
        unsigned byt = (30u << 7) + ((unsigned)((mh << 5) + lane) << 1);
        byt ^= swz ^ (((byt >> 7) & 7) << 4);
        *(unsigned short*)(zb + rb + byt) = f2bf(xselfv);
        if (mh == 0 && lane == 0) {                  // b=31 @ i=0: 1.0 (bias hot-one)
            unsigned byb = (31u << 7);
            byb ^= swz ^ (((byb >> 7) & 7) << 4);
            *(unsigned short*)(zb + rb + byb) = (unsigned short)0x3F80;
        }
    }
}

// ---------- K6: fused v18 (session-best configuration, R17) ----------
__global__ void __launch_bounds__(1024, 8)
k_fused(const float* __restrict__ x, const unsigned* __restrict__ xh,
        const unsigned* __restrict__ ssr2, const int* __restrict__ off,
        const float* __restrict__ coeff, const __hip_bfloat16* __restrict__ bbT,
        float* __restrict__ out, int N) {
    __shared__ __align__(16) unsigned char zb[16 * 4096];   // 16 targets x 2048 bf16 (b-major), swizzled
    __shared__ __align__(16) float pf[16 * 256];            // phase-2 partials; head aliases cofs2+est
    unsigned* cofs2 = (unsigned*)pf;                        // 2 copies [33][16] u32, stride 560 words
    unsigned* est   = ((unsigned*)pf) + 1120;               // 16 slots x 128 words (16B aligned)
    int tid = threadIdx.x;
    int w = tid >> 6, lane = tid & 63;
    int mh = w & 1;
    int t0 = blockIdx.x * 16;

    // hoisted per-round loads (scalars only)
    int tA = t0 + (w >> 1), tB = tA + 8;
    int okA = (tA < N), okB = (tB < N);
    int offA0 = okA ? off[tA] : 0;
    int offA1 = okA ? off[tA + 1] : 0;
    int offB0 = okB ? off[tB] : 0;
    int offB1 = okB ? off[tB + 1] : 0;
    float xsA = okA ? x[((size_t)tA << 6) + (mh << 5) + (lane & 31)] : 0.f;
    float xsB = okB ? x[((size_t)tB << 6) + (mh << 5) + (lane & 31)] : 0.f;

    int s0A = __builtin_amdgcn_readfirstlane(offA0);
    int s1A = __builtin_amdgcn_readfirstlane(offA1);
    int s0B = __builtin_amdgcn_readfirstlane(offB0);
    int s1B = __builtin_amdgcn_readfirstlane(offB1);

    // stage coeff pairs -> LDS (2 bank-offset copies)
    for (int idx = tid; idx < 33 * 16; idx += 1024) {
        int r = idx >> 4, c = idx & 15;
        float lo = (r < 32) ? coeff[r * N_BAS + c] : 0.f;
        float hi = (r < 32 && (c + 16) < N_BAS) ? coeff[r * N_BAS + c + 16] : 0.f;
        _Float16 hl = (_Float16)lo, hh = (_Float16)hi;
        unsigned v = (unsigned)*(unsigned short*)&hl | ((unsigned)*(unsigned short*)&hh << 16);
        cofs2[idx] = v;
        cofs2[idx + 560] = v;
    }
    // stage edge words; pad to x16 with PADW = (N<<5): node N = zero x-row -> exact 0 contribution
    {
        unsigned PADW = (unsigned)N << 5;
        int sgt = mh ? s0B : s0A;
        int sg1 = mh ? s1B : s1A;
        int slot = (w >> 1) + (mh << 3);
        int degS = sg1 - sgt;
        if (degS > 0 && degS <= 128) {
            int pe = (degS + 15) & ~15;
            if (lane < degS)           est[slot * 128 + lane] = ssr2[sgt + lane];
            else if (lane < pe)        est[slot * 128 + lane] = PADW;
            if (lane + 64 < degS)      est[slot * 128 + lane + 64] = ssr2[sgt + lane + 64];
            else if (lane + 64 < pe)   est[slot * 128 + lane + 64] = PADW;
        }
    }
    __syncthreads();

    int l15 = lane & 15, lk = lane >> 4;
    int sbase = lk << 2;
    unsigned xadd2 = (unsigned)(((mh << 4) + l15) << 2);   // xh entry g = mh*16+l15, bytes
    const char* xhB = (const char*)xh;
    unsigned cbase = (unsigned)((lk & 1) * 560);           // cofs copy for this quadrant

    // cross-round est prefetch: both rounds' tile-0 words issue here
    int degA = s1A - s0A, degB = s1B - s0B;
    u32x4 wA0 = {0u, 0u, 0u, 0u}, wB0 = {0u, 0u, 0u, 0u};
    if (degA > 0 && degA <= 128)
        wA0 = *(const u32x4*)((const unsigned char*)(est + (w >> 1) * 128 + sbase));
    if (degB > 0 && degB <= 128)
        wB0 = *(const u32x4*)((const unsigned char*)(est + ((w >> 1) + 8) * 128 + sbase));

    edge_round(zb, cofs2, est, ssr2, xhB, (w >> 1),     s0A, s1A, xsA,
               mh, l15, lk, xadd2, cbase, wA0);
    edge_round(zb, cofs2, est, ssr2, xhB, (w >> 1) + 8, s0B, s1B, xsB,
               mh, l15, lk, xadd2, cbase, wB0);
    __syncthreads();

    // ---- phase 2: wave w -> colblk=w&3, K-quarter kq=w>>2 (512 each, 16 steps);
    //      A from b-major zb (abyte formula + dual XOR); B contiguous 1KB/step from bbT
    {
        int colblk = w & 3, kq = w >> 2;
        const char* bp2 = (const char*)bbT + (((unsigned)(colblk * 4 + kq)) << 14) + ((unsigned)lane << 4);
        unsigned arow = (unsigned)l15 << 12;
        unsigned aswz = (unsigned)((l15 & 7) << 4);
        f32x4 acc2 = {0.f,0.f,0.f,0.f};
#pragma unroll 4
        for (int s = 0; s < 16; ++s) {
            unsigned abyte = (unsigned)((kq << 10) + (s << 6) + (lk << 4));
            abyte ^= aswz ^ (((abyte >> 7) & 7) << 4);
            short8v a = *(const short8v*)(zb + arow + abyte);
            short8v b = *(const short8v*)(bp2 + (s << 10));
            acc2 = __builtin_amdgcn_mfma_f32_16x16x32_bf16(a, b, acc2, 0, 0, 0);
        }
#pragma unroll
        for (int q = 0; q < 4; ++q)                      // D: col=l15, row=lk*4+q (row = target)
            pf[(w << 8) + ((lk << 2) + q) * 16 + l15] = acc2[q];
    }
    __syncthreads();

    // ---- reduce 4 K-quarters + write (1024 threads = 16 targets x 64 cols)
    {
        int row = w, col = lane;
        int cb = col >> 4, cl = col & 15;
        int tt = t0 + row;
        if (tt < N) {
            float v = pf[(((0 << 2) + cb) << 8) + (row << 4) + cl]
                    + pf[(((1 << 2) + cb) << 8) + (row << 4) + cl]
                    + pf[(((2 << 2) + cb) << 8) + (row << 4) + cl]
                    + pf[(((3 << 2) + cb) << 8) + (row << 4) + cl];
            out[((size_t)tt << 6) + col] = v;
        }
    }
}

extern "C" void kernel_launch(void* const* d_in, const int* in_sizes, int n_in,
                              void* d_out, int out_size, void* d_ws, size_t ws_size,
                              hipStream_t stream) {
    const float* x     = (const float*)d_in[0];
    const int*   eidx  = (const int*)d_in[1];   // (2, E)
    const int*   etype = (const int*)d_in[2];
    const float* basis = (const float*)d_in[4];
    const float* coeff = (const float*)d_in[5];
    const float* sw    = (const float*)d_in[6];
    const float* bias  = (const float*)d_in[7];

    const int E = in_sizes[1] / 2;
    const int N = out_size / OUT_F;
    const int NB = (N + 255) >> 8;
    const int* srcv = eidx;
    const int* tgtv = eidx + E;
    float* out = (float*)d_out;

    size_t p = 0;
    auto alloc = [&](size_t bytes) { size_t cur = p; p += (bytes + 255) & ~(size_t)255; return cur; };
    char* base = (char*)d_ws;
    __hip_bfloat16* bbT   = (__hip_bfloat16*)(base + alloc((size_t)OUT_F * KROW * 2));
    int*            gsum  = (int*)(base + alloc(256 * 4));
    int*            gexcl = (int*)(base + alloc((size_t)(NB + 1) * 4));
    int*            bcur  = (int*)(base + alloc((size_t)NB * 4));
    int*            off   = (int*)(base + alloc((size_t)(N + 1) * 4));
    unsigned*       ssr   = (unsigned*)(base + alloc((size_t)E * 4));
    unsigned*       ssr2  = (unsigned*)(base + alloc((size_t)E * 4));
    unsigned*       xh    = (unsigned*)(base + alloc((size_t)(N + 1) * 32 * 4));
    (void)ws_size;

    hipMemsetAsync(gsum, 0, 256 * 4, stream);

    const int nxp = ((N + 1) * 32 + 255) >> 8;
    k_prep<<<512 + nxp + 256, 256, 0, stream>>>(basis, sw, bias, bbT, x, xh, tgtv, gsum, N, E, nxp);
    k_scanB<<<1, 64, 0, stream>>>(gsum, gexcl, bcur, off, NB, N);
    k_b1<<<(E + B1CHUNK - 1) / B1CHUNK, 1024, 0, stream>>>(srcv, tgtv, etype, bcur, ssr, E);
    k_b2<<<NB, 1024, 0, stream>>>(ssr, gexcl, off, ssr2, N);
    k_fused<<<(N + 15) / 16, 1024, 0, stream>>>(x, xh, ssr2, off, coeff, bbT, out, N);
}